// Round 11
// baseline (85.790 us; speedup 1.0000x reference)
//
#include <hip/hip_runtime.h>
#include <hip/hip_bf16.h>

typedef __bf16 bf16x8 __attribute__((ext_vector_type(8)));
typedef float  f32x4  __attribute__((ext_vector_type(4)));
typedef float  f32x16 __attribute__((ext_vector_type(16)));
typedef int    i32x4  __attribute__((ext_vector_type(4)));

#define SEQ 4096
#define CIN 64
#define KBLK 64
#define KSPLIT 8
#define KCHUNK (SEQ / KSPLIT)          // 512 keys per block
#define NTC (KCHUNK / KBLK)            // 8 iters
#define LOG2E 1.44269504088896340736f

__device__ __forceinline__ unsigned cvtpk(float lo, float hi) {
    unsigned r;
    asm("v_cvt_pk_bf16_f32 %0, %1, %2" : "=v"(r) : "v"(lo), "v"(hi));
    return r;
}

// ---------------------------------------------------------------------------
// Kernel 1: fused conv1x1 + PReLU producing Q,K (as [n][4096][32] bf16) and
// Vt in 16-key tiles: [n][kt=256][dv=64][k=16] bf16 (coalesced attn reads).
// Q pre-scaled by log2(e) so attn uses exp2.
// ---------------------------------------------------------------------------
__global__ __launch_bounds__(256, 2) void qkv_gen(
    const float* __restrict__ x,
    const float* __restrict__ w1, const float* __restrict__ b1, const float* __restrict__ a1,
    const float* __restrict__ w2, const float* __restrict__ b2, const float* __restrict__ a2,
    const float* __restrict__ w3, const float* __restrict__ b3, const float* __restrict__ a3,
    __bf16* __restrict__ qws, __bf16* __restrict__ kws, __bf16* __restrict__ vtws)
{
    __shared__ float xs[CIN][64];
    __shared__ float wl[CIN][128];
    __shared__ float bl[128];
    __shared__ float al[4];

    const int t  = threadIdx.x;
    const int n  = blockIdx.x >> 6;
    const int p0 = (blockIdx.x & 63) << 6;

    for (int idx = t; idx < 2048; idx += 256) {
        int j = idx >> 6, c = idx & 63;
        wl[c][j]      = w1[idx];
        wl[c][32 + j] = w2[idx];
    }
    for (int idx = t; idx < 4096; idx += 256) {
        int j = idx >> 6, c = idx & 63;
        wl[c][64 + j] = w3[idx];
    }
    if (t < 32) { bl[t] = b1[t]; bl[32 + t] = b2[t]; }
    if (t >= 128 && t < 192) bl[64 + (t - 128)] = b3[t - 128];
    if (t == 0) { al[0] = a1[0]; al[1] = a2[0]; al[2] = a3[0]; }

    const float* xb = x + ((size_t)n * CIN) * SEQ + p0;
    for (int r = 0; r < 16; ++r) {
        int e = r * 256 + t;
        xs[e >> 6][e & 63] = xb[(size_t)(e >> 6) * SEQ + (e & 63)];
    }
    __syncthreads();

    const int p  = t & 63;
    const int g  = t >> 6;
    const int jb = g << 5;
    const float a = (g == 0) ? al[0] : ((g == 1) ? al[1] : al[2]);

    float acc[32];
    #pragma unroll
    for (int j = 0; j < 32; ++j) acc[j] = bl[jb + j];

    for (int c = 0; c < CIN; ++c) {
        float xv = xs[c][p];
        const f32x4* wr = (const f32x4*)&wl[c][jb];
        #pragma unroll
        for (int j4 = 0; j4 < 8; ++j4) {
            f32x4 wv = wr[j4];
            acc[j4*4+0] = fmaf(wv[0], xv, acc[j4*4+0]);
            acc[j4*4+1] = fmaf(wv[1], xv, acc[j4*4+1]);
            acc[j4*4+2] = fmaf(wv[2], xv, acc[j4*4+2]);
            acc[j4*4+3] = fmaf(wv[3], xv, acc[j4*4+3]);
        }
    }
    #pragma unroll
    for (int j = 0; j < 32; ++j) acc[j] = acc[j] >= 0.f ? acc[j] : a * acc[j];

    const int pg = p0 + p;
    if (g <= 1) {
        const float sc = (g == 0) ? LOG2E : 1.0f;
        __bf16* dst = (g == 0 ? qws : kws) + ((size_t)n * SEQ + pg) * 32;
        #pragma unroll
        for (int v8 = 0; v8 < 4; ++v8) {
            bf16x8 o;
            #pragma unroll
            for (int i = 0; i < 8; ++i) o[i] = (__bf16)(acc[v8*8+i] * sc);
            *(bf16x8*)(dst + v8*8) = o;
        }
    } else {
        // Vt tiles: [n][pg>>4][dv][pg&15]
        __bf16* dst = vtws + (size_t)n * (256 * 1024)
                      + (size_t)(pg >> 4) * 1024 + (jb - 64) * 16 + (pg & 15);
        #pragma unroll
        for (int j = 0; j < 32; ++j) dst[j * 16] = (__bf16)acc[j];
    }
}

// ---------------------------------------------------------------------------
// Kernel 2: flash attention — BARRIER-FREE, LDS-FREE. 32x32 MFMA, in-register
// P (cvt_pk + permlane32), K-SPLIT=8 partials. Each wave independent: 32 q,
// 512 keys, K/V fragments loaded straight from L2 into registers (K/V is
// XCD-L2-resident: n = bid&7). No __shared__, no s_barrier, no vmcnt games —
// TLP (VGPR-bound ~16 waves/CU) + compiler pipelining hide L2 latency.
// ATOMIC=0: bf16 partial O + f32 l per ksplit slice (plain stores).
// ---------------------------------------------------------------------------
template<int ATOMIC>
__global__ __launch_bounds__(256, 4) void attn(
    const __bf16* __restrict__ qws, const __bf16* __restrict__ kws,
    const __bf16* __restrict__ vtws,
    void* __restrict__ Ows, float* __restrict__ lws)
{
    const int t    = threadIdx.x;     // 256 threads, 4 waves
    const int lane = t & 63;
    const int n    = blockIdx.x & 7;
    const int qblk = (blockIdx.x >> 3) & 31;
    const int ks   = blockIdx.x >> 8;
    const int wid  = t >> 6;
    const int l31  = lane & 31;
    const int h    = lane >> 5;
    const int qbase = qblk * 128 + wid * 32;
    const int kbase = ks * KCHUNK;

    const char* kb = (const char*)(kws + (size_t)n * SEQ * 32);      // [4096][32] bf16
    const char* vb = (const char*)(vtws + (size_t)n * (256 * 1024)); // [256][64][16] bf16

    const char* qp = (const char*)(qws + (size_t)n * SEQ * 32)
                     + (size_t)(qbase + l31) * 64 + h * 16;
    const bf16x8 qf0 = *(const bf16x8*)(qp);
    const bf16x8 qf1 = *(const bf16x8*)(qp + 32);

    f32x16 of0 = {}, of1 = {};
    float ls = 0.f;

    for (int tt = 0; tt < NTC; ++tt) {
        const int k0 = kbase + tt * KBLK;
        const char* kp = kb + (size_t)k0 * 64;
        const char* vp = vb + (size_t)(k0 >> 4) * 2048;

        // ---- K fragments (coalesced 16B/lane, from L2) ----
        bf16x8 kf0a = *(const bf16x8*)(kp + l31 * 64 + h * 16);
        bf16x8 kf1a = *(const bf16x8*)(kp + l31 * 64 + 32 + h * 16);
        bf16x8 kf0b = *(const bf16x8*)(kp + (32 + l31) * 64 + h * 16);
        bf16x8 kf1b = *(const bf16x8*)(kp + (32 + l31) * 64 + 32 + h * 16);

        unsigned c0[8], c1[8];

        // ---- S^T tile kti=0 (keys k0..k0+31) + softmax -> c0 ----
        {
            f32x16 s = {};
            s = __builtin_amdgcn_mfma_f32_32x32x16_bf16(kf0a, qf0, s, 0, 0, 0);
            s = __builtin_amdgcn_mfma_f32_32x32x16_bf16(kf1a, qf1, s, 0, 0, 0);
            float p[16];
            #pragma unroll
            for (int r = 0; r < 16; ++r) { p[r] = __builtin_exp2f(s[r]); ls += p[r]; }
            #pragma unroll
            for (int j = 0; j < 4; ++j) {
                c0[j]     = cvtpk(p[2*j],     p[2*j + 1]);
                c0[4 + j] = cvtpk(p[8 + 2*j], p[9 + 2*j]);
            }
            asm("v_permlane32_swap_b32 %0, %1" : "+v"(c0[0]), "+v"(c0[2]));
            asm("v_permlane32_swap_b32 %0, %1" : "+v"(c0[1]), "+v"(c0[3]));
            asm("v_permlane32_swap_b32 %0, %1" : "+v"(c0[4]), "+v"(c0[6]));
            asm("v_permlane32_swap_b32 %0, %1" : "+v"(c0[5]), "+v"(c0[7]));
        }
        // ---- S^T tile kti=1 (keys k0+32..k0+63) + softmax -> c1 ----
        {
            f32x16 s = {};
            s = __builtin_amdgcn_mfma_f32_32x32x16_bf16(kf0b, qf0, s, 0, 0, 0);
            s = __builtin_amdgcn_mfma_f32_32x32x16_bf16(kf1b, qf1, s, 0, 0, 0);
            float p[16];
            #pragma unroll
            for (int r = 0; r < 16; ++r) { p[r] = __builtin_exp2f(s[r]); ls += p[r]; }
            #pragma unroll
            for (int j = 0; j < 4; ++j) {
                c1[j]     = cvtpk(p[2*j],     p[2*j + 1]);
                c1[4 + j] = cvtpk(p[8 + 2*j], p[9 + 2*j]);
            }
            asm("v_permlane32_swap_b32 %0, %1" : "+v"(c1[0]), "+v"(c1[2]));
            asm("v_permlane32_swap_b32 %0, %1" : "+v"(c1[1]), "+v"(c1[3]));
            asm("v_permlane32_swap_b32 %0, %1" : "+v"(c1[4]), "+v"(c1[6]));
            asm("v_permlane32_swap_b32 %0, %1" : "+v"(c1[5]), "+v"(c1[7]));
        }

        // ---- O^T += Vt . P^T : V fragments straight from L2 (coalesced) ----
        #pragma unroll
        for (int s4 = 0; s4 < 4; ++s4) {
            const unsigned* cs = (s4 < 2) ? c0 : c1;
            const int sl = (s4 & 1) * 4;
            i32x4 bi = { (int)cs[sl], (int)cs[sl+1], (int)cs[sl+2], (int)cs[sl+3] };
            bf16x8 pf = __builtin_bit_cast(bf16x8, bi);
            const char* vt_ = vp + s4 * 2048 + l31 * 32 + h * 16;
            bf16x8 vf0 = *(const bf16x8*)(vt_);
            bf16x8 vf1 = *(const bf16x8*)(vt_ + 1024);
            of0 = __builtin_amdgcn_mfma_f32_32x32x16_bf16(vf0, pf, of0, 0, 0, 0);
            of1 = __builtin_amdgcn_mfma_f32_32x32x16_bf16(vf1, pf, of1, 0, 0, 0);
        }
    }

    // ---- epilogue: partial O and l ----
    const int qg = qbase + l31;
    if (ATOMIC) {
        float* Ob = (float*)Ows + (size_t)n * CIN * SEQ;
        #pragma unroll
        for (int r = 0; r < 16; ++r) {
            int dv = (r & 3) + 8 * (r >> 2) + 4 * h;
            unsafeAtomicAdd(Ob + (size_t)dv * SEQ + qg,        of0[r]);
            unsafeAtomicAdd(Ob + (size_t)(dv + 32) * SEQ + qg, of1[r]);
        }
        unsafeAtomicAdd(lws + n * SEQ + qg, ls);
    } else {
        __bf16* Ob = (__bf16*)Ows + (size_t)ks * (8 * CIN * SEQ) + (size_t)n * CIN * SEQ;
        #pragma unroll
        for (int r = 0; r < 16; ++r) {
            int dv = (r & 3) + 8 * (r >> 2) + 4 * h;
            Ob[(size_t)dv * SEQ + qg]        = (__bf16)of0[r];
            Ob[(size_t)(dv + 32) * SEQ + qg] = (__bf16)of1[r];
        }
        float lt = ls + __shfl_xor(ls, 32);
        if (h == 0) lws[(size_t)ks * (8 * SEQ) + n * SEQ + qg] = lt;
    }
}

// ---------------------------------------------------------------------------
// Kernel 3a: lred — lws[0][n][q] := 1 / sum_ks lws[ks][n][q]   (in place)
// ---------------------------------------------------------------------------
__global__ __launch_bounds__(256) void lred(float* __restrict__ lws)
{
    int i = blockIdx.x * 256 + threadIdx.x;        // 32768 = 8n x 4096q
    float s = 0.f;
    #pragma unroll
    for (int ks = 0; ks < KSPLIT; ++ks) s += lws[ks * 32768 + i];
    lws[i] = 1.f / s;
}

// ---------------------------------------------------------------------------
// Kernel 3b: combine8 — out = (sum_ks O_ks) * linv + x   (bf16 partials)
// ---------------------------------------------------------------------------
__global__ __launch_bounds__(256) void combine8(
    const __bf16* __restrict__ O8, const float* __restrict__ linv,
    const float* __restrict__ x, float* __restrict__ out)
{
    const int i = blockIdx.x * 256 + threadIdx.x;  // 262144 slots of 8 outputs
    const int q8 = i & 511;
    const int nd = i >> 9;                          // n*64 + dv
    const int n  = nd >> 6;

    float o[8] = {};
    const __bf16* base = O8 + (size_t)nd * SEQ + q8 * 8;
    #pragma unroll
    for (int ks = 0; ks < KSPLIT; ++ks) {
        bf16x8 v = *(const bf16x8*)(base + (size_t)ks * (8 * CIN * SEQ));
        #pragma unroll
        for (int j = 0; j < 8; ++j) o[j] += (float)v[j];
    }
    const float* ivp = linv + n * SEQ + q8 * 8;
    f32x4 iv0 = *(const f32x4*)(ivp);
    f32x4 iv1 = *(const f32x4*)(ivp + 4);
    const float* xp = x + (size_t)nd * SEQ + q8 * 8;
    f32x4 x0 = *(const f32x4*)(xp);
    f32x4 x1 = *(const f32x4*)(xp + 4);
    f32x4 r0, r1;
    r0[0] = o[0]*iv0[0] + x0[0]; r0[1] = o[1]*iv0[1] + x0[1];
    r0[2] = o[2]*iv0[2] + x0[2]; r0[3] = o[3]*iv0[3] + x0[3];
    r1[0] = o[4]*iv1[0] + x1[0]; r1[1] = o[5]*iv1[1] + x1[1];
    r1[2] = o[6]*iv1[2] + x1[2]; r1[3] = o[7]*iv1[3] + x1[3];
    float* op = out + (size_t)nd * SEQ + q8 * 8;
    *(f32x4*)(op)     = r0;
    *(f32x4*)(op + 4) = r1;
}

// ---------------------------------------------------------------------------
// Kernel 3c: combine1 — legacy (atomic-accumulated f32 buffer)
// ---------------------------------------------------------------------------
__global__ __launch_bounds__(256) void combine1(
    const float* __restrict__ Ows, const float* __restrict__ lws,
    const float* __restrict__ x, float* __restrict__ out)
{
    const int total = 8 * CIN * SEQ / 4;
    for (int i = blockIdx.x * 256 + threadIdx.x; i < total; i += gridDim.x * 256) {
        int q4 = i & 1023;
        int n  = i >> 16;
        f32x4 o4 = *(const f32x4*)(Ows + (size_t)i * 4);
        f32x4 l4 = *(const f32x4*)(lws + (size_t)n * SEQ + q4 * 4);
        f32x4 x4 = *(const f32x4*)(x + (size_t)i * 4);
        f32x4 r;
        r[0] = o4[0] / l4[0] + x4[0];
        r[1] = o4[1] / l4[1] + x4[1];
        r[2] = o4[2] / l4[2] + x4[2];
        r[3] = o4[3] / l4[3] + x4[3];
        *(f32x4*)(out + (size_t)i * 4) = r;
    }
}

extern "C" void kernel_launch(void* const* d_in, const int* in_sizes, int n_in,
                              void* d_out, int out_size, void* d_ws, size_t ws_size,
                              hipStream_t stream)
{
    (void)in_sizes; (void)n_in; (void)out_size;
    const float* x  = (const float*)d_in[0];
    const float* w1 = (const float*)d_in[1];
    const float* b1 = (const float*)d_in[2];
    const float* a1 = (const float*)d_in[3];
    const float* w2 = (const float*)d_in[4];
    const float* b2 = (const float*)d_in[5];
    const float* a2 = (const float*)d_in[6];
    const float* w3 = (const float*)d_in[7];
    const float* b3 = (const float*)d_in[8];
    const float* a3 = (const float*)d_in[9];
    float* out = (float*)d_out;

    char* ws = (char*)d_ws;
    __bf16* qws  = (__bf16*)(ws);                        // 2 MB
    __bf16* kws  = (__bf16*)(ws + (2u << 20));           // 2 MB
    __bf16* vtws = (__bf16*)(ws + (4u << 20));           // 4 MB (tiled layout)

    hipLaunchKernelGGL(qkv_gen, dim3(512), dim3(256), 0, stream,
                       x, w1, b1, a1, w2, b2, a2, w3, b3, a3, qws, kws, vtws);

    const size_t need_split = (8u << 20) + (32u << 20) + (1u << 20);
    if (ws_size >= need_split) {
        // bf16 split partials, no atomics, no memset
        __bf16* O8   = (__bf16*)(ws + (8u << 20));        // 32 MB [8ks][8n][64][4096]
        float*  lws8 = (float*)(ws + (40u << 20));        // 1 MB  [8ks][8n][4096]
        hipLaunchKernelGGL(attn<0>, dim3(8 * 32 * KSPLIT), dim3(256), 0, stream,
                           qws, kws, vtws, (void*)O8, lws8);
        hipLaunchKernelGGL(lred, dim3(128), dim3(256), 0, stream, lws8);
        hipLaunchKernelGGL(combine8, dim3(1024), dim3(256), 0, stream,
                           O8, lws8, x, out);
    } else {
        // legacy atomic fallback
        float* Ows = (float*)(ws + (8u << 20));           // 8 MB
        float* lws = (float*)(ws + (16u << 20));          // 128 KB
        hipMemsetAsync(Ows, 0, (8u << 20) + (128u << 10), stream);
        hipLaunchKernelGGL(attn<1>, dim3(8 * 32 * KSPLIT), dim3(256), 0, stream,
                           qws, kws, vtws, (void*)Ows, lws);
        hipLaunchKernelGGL(combine1, dim3(1024), dim3(256), 0, stream,
                           Ows, lws, x, out);
    }
}

// Round 13
// 83.513 us; speedup vs baseline: 1.0273x; 1.0273x over previous
//
#include <hip/hip_runtime.h>
#include <hip/hip_bf16.h>

typedef __bf16 bf16x8 __attribute__((ext_vector_type(8)));
typedef float  f32x4  __attribute__((ext_vector_type(4)));
typedef float  f32x16 __attribute__((ext_vector_type(16)));
typedef int    i32x4  __attribute__((ext_vector_type(4)));

#define SEQ 4096
#define CIN 64
#define KSPLIT 8
#define KCHUNK (SEQ / KSPLIT)          // 512 keys per block
#define NT32 (KCHUNK / 32)             // 16 tiles of 32 keys
#define LOG2E 1.44269504088896340736f

__device__ __forceinline__ unsigned cvtpk(float lo, float hi) {
    unsigned r;
    asm("v_cvt_pk_bf16_f32 %0, %1, %2" : "=v"(r) : "v"(lo), "v"(hi));
    return r;
}

// ---------------------------------------------------------------------------
// Kernel 1: fused conv1x1 + PReLU producing Q,K (as [n][4096][32] bf16) and
// Vt in 16-key tiles: [n][kt=256][dv=64][k=16] bf16 (coalesced attn reads).
// Q pre-scaled by log2(e) so attn uses exp2.
// ---------------------------------------------------------------------------
__global__ __launch_bounds__(256, 2) void qkv_gen(
    const float* __restrict__ x,
    const float* __restrict__ w1, const float* __restrict__ b1, const float* __restrict__ a1,
    const float* __restrict__ w2, const float* __restrict__ b2, const float* __restrict__ a2,
    const float* __restrict__ w3, const float* __restrict__ b3, const float* __restrict__ a3,
    __bf16* __restrict__ qws, __bf16* __restrict__ kws, __bf16* __restrict__ vtws)
{
    __shared__ float xs[CIN][64];
    __shared__ float wl[CIN][128];
    __shared__ float bl[128];
    __shared__ float al[4];

    const int t  = threadIdx.x;
    const int n  = blockIdx.x >> 6;
    const int p0 = (blockIdx.x & 63) << 6;

    for (int idx = t; idx < 2048; idx += 256) {
        int j = idx >> 6, c = idx & 63;
        wl[c][j]      = w1[idx];
        wl[c][32 + j] = w2[idx];
    }
    for (int idx = t; idx < 4096; idx += 256) {
        int j = idx >> 6, c = idx & 63;
        wl[c][64 + j] = w3[idx];
    }
    if (t < 32) { bl[t] = b1[t]; bl[32 + t] = b2[t]; }
    if (t >= 128 && t < 192) bl[64 + (t - 128)] = b3[t - 128];
    if (t == 0) { al[0] = a1[0]; al[1] = a2[0]; al[2] = a3[0]; }

    const float* xb = x + ((size_t)n * CIN) * SEQ + p0;
    for (int r = 0; r < 16; ++r) {
        int e = r * 256 + t;
        xs[e >> 6][e & 63] = xb[(size_t)(e >> 6) * SEQ + (e & 63)];
    }
    __syncthreads();

    const int p  = t & 63;
    const int g  = t >> 6;
    const int jb = g << 5;
    const float a = (g == 0) ? al[0] : ((g == 1) ? al[1] : al[2]);

    float acc[32];
    #pragma unroll
    for (int j = 0; j < 32; ++j) acc[j] = bl[jb + j];

    for (int c = 0; c < CIN; ++c) {
        float xv = xs[c][p];
        const f32x4* wr = (const f32x4*)&wl[c][jb];
        #pragma unroll
        for (int j4 = 0; j4 < 8; ++j4) {
            f32x4 wv = wr[j4];
            acc[j4*4+0] = fmaf(wv[0], xv, acc[j4*4+0]);
            acc[j4*4+1] = fmaf(wv[1], xv, acc[j4*4+1]);
            acc[j4*4+2] = fmaf(wv[2], xv, acc[j4*4+2]);
            acc[j4*4+3] = fmaf(wv[3], xv, acc[j4*4+3]);
        }
    }
    #pragma unroll
    for (int j = 0; j < 32; ++j) acc[j] = acc[j] >= 0.f ? acc[j] : a * acc[j];

    const int pg = p0 + p;
    if (g <= 1) {
        const float sc = (g == 0) ? LOG2E : 1.0f;
        __bf16* dst = (g == 0 ? qws : kws) + ((size_t)n * SEQ + pg) * 32;
        #pragma unroll
        for (int v8 = 0; v8 < 4; ++v8) {
            bf16x8 o;
            #pragma unroll
            for (int i = 0; i < 8; ++i) o[i] = (__bf16)(acc[v8*8+i] * sc);
            *(bf16x8*)(dst + v8*8) = o;
        }
    } else {
        // Vt tiles: [n][pg>>4][dv][pg&15]
        __bf16* dst = vtws + (size_t)n * (256 * 1024)
                      + (size_t)(pg >> 4) * 1024 + (jb - 64) * 16 + (pg & 15);
        #pragma unroll
        for (int j = 0; j < 32; ++j) dst[j * 16] = (__bf16)acc[j];
    }
}

// ---------------------------------------------------------------------------
// Kernel 2: flash attention — barrier-free, LDS-free, register-diet.
// Per-32-key-tile interleave: {2 K loads, 4 V loads (P-independent, hoisted),
// 2 S-MFMA, 16 exp2, pack -> c[8], 4 PV-MFMA}.
// r12 BUG FIX: vb tile offset is (kbase>>4)*2048 bytes (each 16-key Vt tile
// is 64dv x 16k x 2B = 2048 B); r12 used *1024 -> ks>0 blocks read wrong V.
// K-SPLIT=8 partials; grid 2048 = 8n x 32qblk x 8ks, 4 waves x 32q.
// ---------------------------------------------------------------------------
template<int ATOMIC>
__global__ __launch_bounds__(256, 4) void attn(
    const __bf16* __restrict__ qws, const __bf16* __restrict__ kws,
    const __bf16* __restrict__ vtws,
    void* __restrict__ Ows, float* __restrict__ lws)
{
    const int t    = threadIdx.x;     // 256 threads, 4 waves
    const int lane = t & 63;
    const int n    = blockIdx.x & 7;
    const int qblk = (blockIdx.x >> 3) & 31;
    const int ks   = blockIdx.x >> 8;
    const int wid  = t >> 6;
    const int l31  = lane & 31;
    const int h    = lane >> 5;
    const int qbase = qblk * 128 + wid * 32;
    const int kbase = ks * KCHUNK;
    const int koff = l31 * 64 + h * 16;    // K frag lane offset
    const int voff = l31 * 32 + h * 16;    // V frag lane offset

    const char* kb = (const char*)(kws + (size_t)n * SEQ * 32) + (size_t)kbase * 64;
    const char* vb = (const char*)(vtws + (size_t)n * (256 * 1024))
                     + (size_t)(kbase >> 4) * 2048;

    const char* qp = (const char*)(qws + (size_t)n * SEQ * 32)
                     + (size_t)(qbase + l31) * 64 + h * 16;
    const bf16x8 qf0 = *(const bf16x8*)(qp);
    const bf16x8 qf1 = *(const bf16x8*)(qp + 32);

    f32x16 of0 = {}, of1 = {};
    f32x4 ls4 = {0.f, 0.f, 0.f, 0.f};

    #pragma unroll 2
    for (int tile = 0; tile < NT32; ++tile) {
        const char* kp = kb + (size_t)tile * 2048;   // 32 keys x 64 B
        const char* vp = vb + (size_t)tile * 4096;   // two 16-key vt tiles (2 KB each)

        // ---- loads for this tile (V independent of P -> hides under softmax) ----
        bf16x8 kfa  = *(const bf16x8*)(kp + koff);
        bf16x8 kfb  = *(const bf16x8*)(kp + koff + 32);
        bf16x8 vf00 = *(const bf16x8*)(vp + voff);
        bf16x8 vf01 = *(const bf16x8*)(vp + voff + 1024);
        bf16x8 vf10 = *(const bf16x8*)(vp + voff + 2048);
        bf16x8 vf11 = *(const bf16x8*)(vp + voff + 3072);

        // ---- S^T tile (32 keys x 32 q): 2 chained MFMAs over d ----
        f32x16 s = {};
        s = __builtin_amdgcn_mfma_f32_32x32x16_bf16(kfa, qf0, s, 0, 0, 0);
        s = __builtin_amdgcn_mfma_f32_32x32x16_bf16(kfb, qf1, s, 0, 0, 0);

        // ---- softmax: exp2, vector row-sum, pack to PV B-frag layout ----
        float p[16];
        #pragma unroll
        for (int r = 0; r < 16; ++r) p[r] = __builtin_exp2f(s[r]);
        f32x4 e0 = { p[0], p[1], p[2],  p[3]  };
        f32x4 e1 = { p[4], p[5], p[6],  p[7]  };
        f32x4 e2 = { p[8], p[9], p[10], p[11] };
        f32x4 e3 = { p[12], p[13], p[14], p[15] };
        ls4 += e0 + e1 + e2 + e3;

        unsigned c[8];
        #pragma unroll
        for (int j = 0; j < 4; ++j) {
            c[j]     = cvtpk(p[2*j],     p[2*j + 1]);
            c[4 + j] = cvtpk(p[8 + 2*j], p[9 + 2*j]);
        }
        asm("v_permlane32_swap_b32 %0, %1" : "+v"(c[0]), "+v"(c[2]));
        asm("v_permlane32_swap_b32 %0, %1" : "+v"(c[1]), "+v"(c[3]));
        asm("v_permlane32_swap_b32 %0, %1" : "+v"(c[4]), "+v"(c[6]));
        asm("v_permlane32_swap_b32 %0, %1" : "+v"(c[5]), "+v"(c[7]));

        // ---- O^T += Vt . P^T : 2 key-steps x 2 dv-halves ----
        i32x4 b0 = { (int)c[0], (int)c[1], (int)c[2], (int)c[3] };
        i32x4 b1 = { (int)c[4], (int)c[5], (int)c[6], (int)c[7] };
        bf16x8 pf0 = __builtin_bit_cast(bf16x8, b0);
        bf16x8 pf1 = __builtin_bit_cast(bf16x8, b1);
        of0 = __builtin_amdgcn_mfma_f32_32x32x16_bf16(vf00, pf0, of0, 0, 0, 0);
        of1 = __builtin_amdgcn_mfma_f32_32x32x16_bf16(vf01, pf0, of1, 0, 0, 0);
        of0 = __builtin_amdgcn_mfma_f32_32x32x16_bf16(vf10, pf1, of0, 0, 0, 0);
        of1 = __builtin_amdgcn_mfma_f32_32x32x16_bf16(vf11, pf1, of1, 0, 0, 0);
    }

    // ---- epilogue: partial O and l ----
    const float ls = ls4[0] + ls4[1] + ls4[2] + ls4[3];
    const int qg = qbase + l31;
    if (ATOMIC) {
        float* Ob = (float*)Ows + (size_t)n * CIN * SEQ;
        #pragma unroll
        for (int r = 0; r < 16; ++r) {
            int dv = (r & 3) + 8 * (r >> 2) + 4 * h;
            unsafeAtomicAdd(Ob + (size_t)dv * SEQ + qg,        of0[r]);
            unsafeAtomicAdd(Ob + (size_t)(dv + 32) * SEQ + qg, of1[r]);
        }
        unsafeAtomicAdd(lws + n * SEQ + qg, ls);
    } else {
        __bf16* Ob = (__bf16*)Ows + (size_t)ks * (8 * CIN * SEQ) + (size_t)n * CIN * SEQ;
        #pragma unroll
        for (int r = 0; r < 16; ++r) {
            int dv = (r & 3) + 8 * (r >> 2) + 4 * h;
            Ob[(size_t)dv * SEQ + qg]        = (__bf16)of0[r];
            Ob[(size_t)(dv + 32) * SEQ + qg] = (__bf16)of1[r];
        }
        float lt = ls + __shfl_xor(ls, 32);
        if (h == 0) lws[(size_t)ks * (8 * SEQ) + n * SEQ + qg] = lt;
    }
}

// ---------------------------------------------------------------------------
// Kernel 3a: lred — lws[0][n][q] := 1 / sum_ks lws[ks][n][q]   (in place)
// ---------------------------------------------------------------------------
__global__ __launch_bounds__(256) void lred(float* __restrict__ lws)
{
    int i = blockIdx.x * 256 + threadIdx.x;        // 32768 = 8n x 4096q
    float s = 0.f;
    #pragma unroll
    for (int ks = 0; ks < KSPLIT; ++ks) s += lws[ks * 32768 + i];
    lws[i] = 1.f / s;
}

// ---------------------------------------------------------------------------
// Kernel 3b: combine8 — out = (sum_ks O_ks) * linv + x   (bf16 partials)
// ---------------------------------------------------------------------------
__global__ __launch_bounds__(256) void combine8(
    const __bf16* __restrict__ O8, const float* __restrict__ linv,
    const float* __restrict__ x, float* __restrict__ out)
{
    const int i = blockIdx.x * 256 + threadIdx.x;  // 262144 slots of 8 outputs
    const int q8 = i & 511;
    const int nd = i >> 9;                          // n*64 + dv
    const int n  = nd >> 6;

    float o[8] = {};
    const __bf16* base = O8 + (size_t)nd * SEQ + q8 * 8;
    #pragma unroll
    for (int ks = 0; ks < KSPLIT; ++ks) {
        bf16x8 v = *(const bf16x8*)(base + (size_t)ks * (8 * CIN * SEQ));
        #pragma unroll
        for (int j = 0; j < 8; ++j) o[j] += (float)v[j];
    }
    const float* ivp = linv + n * SEQ + q8 * 8;
    f32x4 iv0 = *(const f32x4*)(ivp);
    f32x4 iv1 = *(const f32x4*)(ivp + 4);
    const float* xp = x + (size_t)nd * SEQ + q8 * 8;
    f32x4 x0 = *(const f32x4*)(xp);
    f32x4 x1 = *(const f32x4*)(xp + 4);
    f32x4 r0, r1;
    r0[0] = o[0]*iv0[0] + x0[0]; r0[1] = o[1]*iv0[1] + x0[1];
    r0[2] = o[2]*iv0[2] + x0[2]; r0[3] = o[3]*iv0[3] + x0[3];
    r1[0] = o[4]*iv1[0] + x1[0]; r1[1] = o[5]*iv1[1] + x1[1];
    r1[2] = o[6]*iv1[2] + x1[2]; r1[3] = o[7]*iv1[3] + x1[3];
    float* op = out + (size_t)nd * SEQ + q8 * 8;
    *(f32x4*)(op)     = r0;
    *(f32x4*)(op + 4) = r1;
}

// ---------------------------------------------------------------------------
// Kernel 3c: combine1 — legacy (atomic-accumulated f32 buffer)
// ---------------------------------------------------------------------------
__global__ __launch_bounds__(256) void combine1(
    const float* __restrict__ Ows, const float* __restrict__ lws,
    const float* __restrict__ x, float* __restrict__ out)
{
    const int total = 8 * CIN * SEQ / 4;
    for (int i = blockIdx.x * 256 + threadIdx.x; i < total; i += gridDim.x * 256) {
        int q4 = i & 1023;
        int n  = i >> 16;
        f32x4 o4 = *(const f32x4*)(Ows + (size_t)i * 4);
        f32x4 l4 = *(const f32x4*)(lws + (size_t)n * SEQ + q4 * 4);
        f32x4 x4 = *(const f32x4*)(x + (size_t)i * 4);
        f32x4 r;
        r[0] = o4[0] / l4[0] + x4[0];
        r[1] = o4[1] / l4[1] + x4[1];
        r[2] = o4[2] / l4[2] + x4[2];
        r[3] = o4[3] / l4[3] + x4[3];
        *(f32x4*)(out + (size_t)i * 4) = r;
    }
}

extern "C" void kernel_launch(void* const* d_in, const int* in_sizes, int n_in,
                              void* d_out, int out_size, void* d_ws, size_t ws_size,
                              hipStream_t stream)
{
    (void)in_sizes; (void)n_in; (void)out_size;
    const float* x  = (const float*)d_in[0];
    const float* w1 = (const float*)d_in[1];
    const float* b1 = (const float*)d_in[2];
    const float* a1 = (const float*)d_in[3];
    const float* w2 = (const float*)d_in[4];
    const float* b2 = (const float*)d_in[5];
    const float* a2 = (const float*)d_in[6];
    const float* w3 = (const float*)d_in[7];
    const float* b3 = (const float*)d_in[8];
    const float* a3 = (const float*)d_in[9];
    float* out = (float*)d_out;

    char* ws = (char*)d_ws;
    __bf16* qws  = (__bf16*)(ws);                        // 2 MB
    __bf16* kws  = (__bf16*)(ws + (2u << 20));           // 2 MB
    __bf16* vtws = (__bf16*)(ws + (4u << 20));           // 4 MB (tiled layout)

    hipLaunchKernelGGL(qkv_gen, dim3(512), dim3(256), 0, stream,
                       x, w1, b1, a1, w2, b2, a2, w3, b3, a3, qws, kws, vtws);

    const size_t need_split = (8u << 20) + (32u << 20) + (1u << 20);
    if (ws_size >= need_split) {
        // bf16 split partials, no atomics, no memset
        __bf16* O8   = (__bf16*)(ws + (8u << 20));        // 32 MB [8ks][8n][64][4096]
        float*  lws8 = (float*)(ws + (40u << 20));        // 1 MB  [8ks][8n][4096]
        hipLaunchKernelGGL(attn<0>, dim3(8 * 32 * KSPLIT), dim3(256), 0, stream,
                           qws, kws, vtws, (void*)O8, lws8);
        hipLaunchKernelGGL(lred, dim3(128), dim3(256), 0, stream, lws8);
        hipLaunchKernelGGL(combine8, dim3(1024), dim3(256), 0, stream,
                           O8, lws8, x, out);
    } else {
        // legacy atomic fallback
        float* Ows = (float*)(ws + (8u << 20));           // 8 MB
        float* lws = (float*)(ws + (16u << 20));          // 128 KB
        hipMemsetAsync(Ows, 0, (8u << 20) + (128u << 10), stream);
        hipLaunchKernelGGL(attn<1>, dim3(8 * 32 * KSPLIT), dim3(256), 0, stream,
                           qws, kws, vtws, (void*)Ows, lws);
        hipLaunchKernelGGL(combine1, dim3(1024), dim3(256), 0, stream,
                           Ows, lws, x, out);
    }
}

// Round 14
// 82.368 us; speedup vs baseline: 1.0415x; 1.0139x over previous
//
#include <hip/hip_runtime.h>
#include <hip/hip_bf16.h>

typedef __bf16 bf16x8 __attribute__((ext_vector_type(8)));
typedef float  f32x4  __attribute__((ext_vector_type(4)));
typedef float  f32x16 __attribute__((ext_vector_type(16)));
typedef int    i32x4  __attribute__((ext_vector_type(4)));

#define SEQ 4096
#define CIN 64
#define KSPLIT 8
#define KCHUNK (SEQ / KSPLIT)          // 512 keys per block
#define NT32 (KCHUNK / 32)             // 16 tiles of 32 keys
#define LOG2E 1.44269504088896340736f

__device__ __forceinline__ unsigned cvtpk(float lo, float hi) {
    unsigned r;
    asm("v_cvt_pk_bf16_f32 %0, %1, %2" : "=v"(r) : "v"(lo), "v"(hi));
    return r;
}

// ---------------------------------------------------------------------------
// Kernel 1: fused conv1x1 + PReLU producing Q,K (as [n][4096][32] bf16) and
// Vt in 16-key tiles: [n][kt=256][dv=64][k=16] bf16 (coalesced attn reads).
// Q pre-scaled by log2(e) so attn uses exp2.
// ---------------------------------------------------------------------------
__global__ __launch_bounds__(256, 2) void qkv_gen(
    const float* __restrict__ x,
    const float* __restrict__ w1, const float* __restrict__ b1, const float* __restrict__ a1,
    const float* __restrict__ w2, const float* __restrict__ b2, const float* __restrict__ a2,
    const float* __restrict__ w3, const float* __restrict__ b3, const float* __restrict__ a3,
    __bf16* __restrict__ qws, __bf16* __restrict__ kws, __bf16* __restrict__ vtws)
{
    __shared__ float xs[CIN][64];
    __shared__ float wl[CIN][128];
    __shared__ float bl[128];
    __shared__ float al[4];

    const int t  = threadIdx.x;
    const int n  = blockIdx.x >> 6;
    const int p0 = (blockIdx.x & 63) << 6;

    for (int idx = t; idx < 2048; idx += 256) {
        int j = idx >> 6, c = idx & 63;
        wl[c][j]      = w1[idx];
        wl[c][32 + j] = w2[idx];
    }
    for (int idx = t; idx < 4096; idx += 256) {
        int j = idx >> 6, c = idx & 63;
        wl[c][64 + j] = w3[idx];
    }
    if (t < 32) { bl[t] = b1[t]; bl[32 + t] = b2[t]; }
    if (t >= 128 && t < 192) bl[64 + (t - 128)] = b3[t - 128];
    if (t == 0) { al[0] = a1[0]; al[1] = a2[0]; al[2] = a3[0]; }

    const float* xb = x + ((size_t)n * CIN) * SEQ + p0;
    for (int r = 0; r < 16; ++r) {
        int e = r * 256 + t;
        xs[e >> 6][e & 63] = xb[(size_t)(e >> 6) * SEQ + (e & 63)];
    }
    __syncthreads();

    const int p  = t & 63;
    const int g  = t >> 6;
    const int jb = g << 5;
    const float a = (g == 0) ? al[0] : ((g == 1) ? al[1] : al[2]);

    float acc[32];
    #pragma unroll
    for (int j = 0; j < 32; ++j) acc[j] = bl[jb + j];

    for (int c = 0; c < CIN; ++c) {
        float xv = xs[c][p];
        const f32x4* wr = (const f32x4*)&wl[c][jb];
        #pragma unroll
        for (int j4 = 0; j4 < 8; ++j4) {
            f32x4 wv = wr[j4];
            acc[j4*4+0] = fmaf(wv[0], xv, acc[j4*4+0]);
            acc[j4*4+1] = fmaf(wv[1], xv, acc[j4*4+1]);
            acc[j4*4+2] = fmaf(wv[2], xv, acc[j4*4+2]);
            acc[j4*4+3] = fmaf(wv[3], xv, acc[j4*4+3]);
        }
    }
    #pragma unroll
    for (int j = 0; j < 32; ++j) acc[j] = acc[j] >= 0.f ? acc[j] : a * acc[j];

    const int pg = p0 + p;
    if (g <= 1) {
        const float sc = (g == 0) ? LOG2E : 1.0f;
        __bf16* dst = (g == 0 ? qws : kws) + ((size_t)n * SEQ + pg) * 32;
        #pragma unroll
        for (int v8 = 0; v8 < 4; ++v8) {
            bf16x8 o;
            #pragma unroll
            for (int i = 0; i < 8; ++i) o[i] = (__bf16)(acc[v8*8+i] * sc);
            *(bf16x8*)(dst + v8*8) = o;
        }
    } else {
        // Vt tiles: [n][pg>>4][dv][pg&15]
        __bf16* dst = vtws + (size_t)n * (256 * 1024)
                      + (size_t)(pg >> 4) * 1024 + (jb - 64) * 16 + (pg & 15);
        #pragma unroll
        for (int j = 0; j < 32; ++j) dst[j * 16] = (__bf16)acc[j];
    }
}

// ---------------------------------------------------------------------------
// Kernel 2: flash attention — barrier-free, LDS-free, CROSS-TILE PREFETCH.
// Manual 2x-unrolled pipeline with two NAMED fragment sets (A/B): tile t+1's
// 6 L2 loads are issued BEFORE tile t's compute, hiding ~300cy L2 latency
// under ~240cy of MFMA+exp2+pack. setprio(1) around MFMA clusters (waves at
// independent phases -> scheduler favors compute-ready waves, m191).
// K-SPLIT=8 bf16 partials; grid 2048 = 8n x 32qblk x 8ks, 4 waves x 32q.
// ---------------------------------------------------------------------------
struct Frags {
    bf16x8 ka, kb, v00, v01, v10, v11;
};

__device__ __forceinline__ Frags ldf(const char* kb_, const char* vb_,
                                     int tile, int koff, int voff)
{
    Frags f;
    const char* kp = kb_ + (size_t)tile * 2048;   // 32 keys x 64 B
    const char* vp = vb_ + (size_t)tile * 4096;   // two 2KB 16-key vt tiles
    f.ka  = *(const bf16x8*)(kp + koff);
    f.kb  = *(const bf16x8*)(kp + koff + 32);
    f.v00 = *(const bf16x8*)(vp + voff);
    f.v01 = *(const bf16x8*)(vp + voff + 1024);
    f.v10 = *(const bf16x8*)(vp + voff + 2048);
    f.v11 = *(const bf16x8*)(vp + voff + 3072);
    return f;
}

template<int ATOMIC>
__global__ __launch_bounds__(256, 4) void attn(
    const __bf16* __restrict__ qws, const __bf16* __restrict__ kws,
    const __bf16* __restrict__ vtws,
    void* __restrict__ Ows, float* __restrict__ lws)
{
    const int t    = threadIdx.x;     // 256 threads, 4 waves
    const int lane = t & 63;
    const int n    = blockIdx.x & 7;
    const int qblk = (blockIdx.x >> 3) & 31;
    const int ks   = blockIdx.x >> 8;
    const int wid  = t >> 6;
    const int l31  = lane & 31;
    const int h    = lane >> 5;
    const int qbase = qblk * 128 + wid * 32;
    const int kbase = ks * KCHUNK;
    const int koff = l31 * 64 + h * 16;
    const int voff = l31 * 32 + h * 16;

    const char* kb = (const char*)(kws + (size_t)n * SEQ * 32) + (size_t)kbase * 64;
    const char* vb = (const char*)(vtws + (size_t)n * (256 * 1024))
                     + (size_t)(kbase >> 4) * 2048;

    const char* qp = (const char*)(qws + (size_t)n * SEQ * 32)
                     + (size_t)(qbase + l31) * 64 + h * 16;
    const bf16x8 qf0 = *(const bf16x8*)(qp);
    const bf16x8 qf1 = *(const bf16x8*)(qp + 32);

    f32x16 of0 = {}, of1 = {};
    f32x4 ls4 = {0.f, 0.f, 0.f, 0.f};

    // ---- per-tile compute body (operates on a named fragment set) ----
    auto body = [&](const Frags& F) {
        f32x16 s = {};
        __builtin_amdgcn_s_setprio(1);
        s = __builtin_amdgcn_mfma_f32_32x32x16_bf16(F.ka, qf0, s, 0, 0, 0);
        s = __builtin_amdgcn_mfma_f32_32x32x16_bf16(F.kb, qf1, s, 0, 0, 0);
        __builtin_amdgcn_s_setprio(0);

        float p[16];
        #pragma unroll
        for (int r = 0; r < 16; ++r) p[r] = __builtin_exp2f(s[r]);
        f32x4 e0 = { p[0], p[1], p[2],  p[3]  };
        f32x4 e1 = { p[4], p[5], p[6],  p[7]  };
        f32x4 e2 = { p[8], p[9], p[10], p[11] };
        f32x4 e3 = { p[12], p[13], p[14], p[15] };
        ls4 += e0 + e1 + e2 + e3;

        unsigned c[8];
        #pragma unroll
        for (int j = 0; j < 4; ++j) {
            c[j]     = cvtpk(p[2*j],     p[2*j + 1]);
            c[4 + j] = cvtpk(p[8 + 2*j], p[9 + 2*j]);
        }
        asm("v_permlane32_swap_b32 %0, %1" : "+v"(c[0]), "+v"(c[2]));
        asm("v_permlane32_swap_b32 %0, %1" : "+v"(c[1]), "+v"(c[3]));
        asm("v_permlane32_swap_b32 %0, %1" : "+v"(c[4]), "+v"(c[6]));
        asm("v_permlane32_swap_b32 %0, %1" : "+v"(c[5]), "+v"(c[7]));

        i32x4 b0 = { (int)c[0], (int)c[1], (int)c[2], (int)c[3] };
        i32x4 b1 = { (int)c[4], (int)c[5], (int)c[6], (int)c[7] };
        bf16x8 pf0 = __builtin_bit_cast(bf16x8, b0);
        bf16x8 pf1 = __builtin_bit_cast(bf16x8, b1);
        __builtin_amdgcn_s_setprio(1);
        of0 = __builtin_amdgcn_mfma_f32_32x32x16_bf16(F.v00, pf0, of0, 0, 0, 0);
        of1 = __builtin_amdgcn_mfma_f32_32x32x16_bf16(F.v01, pf0, of1, 0, 0, 0);
        of0 = __builtin_amdgcn_mfma_f32_32x32x16_bf16(F.v10, pf1, of0, 0, 0, 0);
        of1 = __builtin_amdgcn_mfma_f32_32x32x16_bf16(F.v11, pf1, of1, 0, 0, 0);
        __builtin_amdgcn_s_setprio(0);
    };

    // ---- software pipeline: loads for t+1 issued before compute of t ----
    Frags A = ldf(kb, vb, 0, koff, voff);
    #pragma unroll 1
    for (int tile = 0; tile < NT32; tile += 2) {
        Frags B = ldf(kb, vb, tile + 1, koff, voff);   // prefetch odd tile
        body(A);                                        // compute even tile
        if (tile + 2 < NT32)
            A = ldf(kb, vb, tile + 2, koff, voff);      // prefetch next even
        body(B);                                        // compute odd tile
    }

    // ---- epilogue: partial O and l ----
    const float ls = ls4[0] + ls4[1] + ls4[2] + ls4[3];
    const int qg = qbase + l31;
    if (ATOMIC) {
        float* Ob = (float*)Ows + (size_t)n * CIN * SEQ;
        #pragma unroll
        for (int r = 0; r < 16; ++r) {
            int dv = (r & 3) + 8 * (r >> 2) + 4 * h;
            unsafeAtomicAdd(Ob + (size_t)dv * SEQ + qg,        of0[r]);
            unsafeAtomicAdd(Ob + (size_t)(dv + 32) * SEQ + qg, of1[r]);
        }
        unsafeAtomicAdd(lws + n * SEQ + qg, ls);
    } else {
        __bf16* Ob = (__bf16*)Ows + (size_t)ks * (8 * CIN * SEQ) + (size_t)n * CIN * SEQ;
        #pragma unroll
        for (int r = 0; r < 16; ++r) {
            int dv = (r & 3) + 8 * (r >> 2) + 4 * h;
            Ob[(size_t)dv * SEQ + qg]        = (__bf16)of0[r];
            Ob[(size_t)(dv + 32) * SEQ + qg] = (__bf16)of1[r];
        }
        float lt = ls + __shfl_xor(ls, 32);
        if (h == 0) lws[(size_t)ks * (8 * SEQ) + n * SEQ + qg] = lt;
    }
}

// ---------------------------------------------------------------------------
// Kernel 3a: combine8 — out = (sum_ks O_ks) / (sum_ks l_ks) + x
// (l-reduction folded in: lws is 1 MB, L2-resident, redundant reads ~free)
// ---------------------------------------------------------------------------
__global__ __launch_bounds__(256) void combine8(
    const __bf16* __restrict__ O8, const float* __restrict__ lws,
    const float* __restrict__ x, float* __restrict__ out)
{
    const int i = blockIdx.x * 256 + threadIdx.x;  // 262144 slots of 8 outputs
    const int q8 = i & 511;
    const int nd = i >> 9;                          // n*64 + dv
    const int n  = nd >> 6;

    float o[8] = {};
    const __bf16* base = O8 + (size_t)nd * SEQ + q8 * 8;
    #pragma unroll
    for (int ks = 0; ks < KSPLIT; ++ks) {
        bf16x8 v = *(const bf16x8*)(base + (size_t)ks * (8 * CIN * SEQ));
        #pragma unroll
        for (int j = 0; j < 8; ++j) o[j] += (float)v[j];
    }

    float lsum[8] = {};
    const float* lp = lws + n * SEQ + q8 * 8;
    #pragma unroll
    for (int ks = 0; ks < KSPLIT; ++ks) {
        f32x4 a = *(const f32x4*)(lp + ks * 32768);
        f32x4 b = *(const f32x4*)(lp + ks * 32768 + 4);
        lsum[0] += a[0]; lsum[1] += a[1]; lsum[2] += a[2]; lsum[3] += a[3];
        lsum[4] += b[0]; lsum[5] += b[1]; lsum[6] += b[2]; lsum[7] += b[3];
    }

    const float* xp = x + (size_t)nd * SEQ + q8 * 8;
    f32x4 x0 = *(const f32x4*)(xp);
    f32x4 x1 = *(const f32x4*)(xp + 4);
    f32x4 r0, r1;
    r0[0] = o[0]/lsum[0] + x0[0]; r0[1] = o[1]/lsum[1] + x0[1];
    r0[2] = o[2]/lsum[2] + x0[2]; r0[3] = o[3]/lsum[3] + x0[3];
    r1[0] = o[4]/lsum[4] + x1[0]; r1[1] = o[5]/lsum[5] + x1[1];
    r1[2] = o[6]/lsum[6] + x1[2]; r1[3] = o[7]/lsum[7] + x1[3];
    float* op = out + (size_t)nd * SEQ + q8 * 8;
    *(f32x4*)(op)     = r0;
    *(f32x4*)(op + 4) = r1;
}

// ---------------------------------------------------------------------------
// Kernel 3b: combine1 — legacy (atomic-accumulated f32 buffer)
// ---------------------------------------------------------------------------
__global__ __launch_bounds__(256) void combine1(
    const float* __restrict__ Ows, const float* __restrict__ lws,
    const float* __restrict__ x, float* __restrict__ out)
{
    const int total = 8 * CIN * SEQ / 4;
    for (int i = blockIdx.x * 256 + threadIdx.x; i < total; i += gridDim.x * 256) {
        int q4 = i & 1023;
        int n  = i >> 16;
        f32x4 o4 = *(const f32x4*)(Ows + (size_t)i * 4);
        f32x4 l4 = *(const f32x4*)(lws + (size_t)n * SEQ + q4 * 4);
        f32x4 x4 = *(const f32x4*)(x + (size_t)i * 4);
        f32x4 r;
        r[0] = o4[0] / l4[0] + x4[0];
        r[1] = o4[1] / l4[1] + x4[1];
        r[2] = o4[2] / l4[2] + x4[2];
        r[3] = o4[3] / l4[3] + x4[3];
        *(f32x4*)(out + (size_t)i * 4) = r;
    }
}

extern "C" void kernel_launch(void* const* d_in, const int* in_sizes, int n_in,
                              void* d_out, int out_size, void* d_ws, size_t ws_size,
                              hipStream_t stream)
{
    (void)in_sizes; (void)n_in; (void)out_size;
    const float* x  = (const float*)d_in[0];
    const float* w1 = (const float*)d_in[1];
    const float* b1 = (const float*)d_in[2];
    const float* a1 = (const float*)d_in[3];
    const float* w2 = (const float*)d_in[4];
    const float* b2 = (const float*)d_in[5];
    const float* a2 = (const float*)d_in[6];
    const float* w3 = (const float*)d_in[7];
    const float* b3 = (const float*)d_in[8];
    const float* a3 = (const float*)d_in[9];
    float* out = (float*)d_out;

    char* ws = (char*)d_ws;
    __bf16* qws  = (__bf16*)(ws);                        // 2 MB
    __bf16* kws  = (__bf16*)(ws + (2u << 20));           // 2 MB
    __bf16* vtws = (__bf16*)(ws + (4u << 20));           // 4 MB (tiled layout)

    hipLaunchKernelGGL(qkv_gen, dim3(512), dim3(256), 0, stream,
                       x, w1, b1, a1, w2, b2, a2, w3, b3, a3, qws, kws, vtws);

    const size_t need_split = (8u << 20) + (32u << 20) + (1u << 20);
    if (ws_size >= need_split) {
        // bf16 split partials, no atomics, no memset
        __bf16* O8   = (__bf16*)(ws + (8u << 20));        // 32 MB [8ks][8n][64][4096]
        float*  lws8 = (float*)(ws + (40u << 20));        // 1 MB  [8ks][8n][4096]
        hipLaunchKernelGGL(attn<0>, dim3(8 * 32 * KSPLIT), dim3(256), 0, stream,
                           qws, kws, vtws, (void*)O8, lws8);
        hipLaunchKernelGGL(combine8, dim3(1024), dim3(256), 0, stream,
                           O8, lws8, x, out);
    } else {
        // legacy atomic fallback
        float* Ows = (float*)(ws + (8u << 20));           // 8 MB
        float* lws = (float*)(ws + (16u << 20));          // 128 KB
        hipMemsetAsync(Ows, 0, (8u << 20) + (128u << 10), stream);
        hipLaunchKernelGGL(attn<1>, dim3(8 * 32 * KSPLIT), dim3(256), 0, stream,
                           qws, kws, vtws, (void*)Ows, lws);
        hipLaunchKernelGGL(combine1, dim3(1024), dim3(256), 0, stream,
                           Ows, lws, x, out);
    }
}